// Round 10
// baseline (290.838 us; speedup 1.0000x reference)
//
#include <hip/hip_runtime.h>
#include <hip/hip_bf16.h>

#define HEADS 8
#define MPAD  208   // padded node count (13*16)
#define KPAD  224   // padded s-dim (7*32)
#define HROWS 112   // rows per M-half in gemm
#define NB    208   // score blocks: 26 dtiles x 8 heads

typedef __attribute__((ext_vector_type(8))) short short8v;
typedef __attribute__((ext_vector_type(4))) float float4v;

static __device__ __forceinline__ unsigned short f2bf(float f) {
    unsigned int u = __float_as_uint(f);
    u += 0x7FFF + ((u >> 16) & 1);          // RNE
    return (unsigned short)(u >> 16);
}
static __device__ __forceinline__ float bf2f(unsigned short h) {
    return __uint_as_float(((unsigned int)h) << 16);
}

// ---------------- MFMA split-bf16 dual GEMM, W-stationary ----------------
// Writes T-layout planes outT[2][2048][KPAD] (for MFMA agg B-frags) AND
// R-layout planes outR[2][KPAD][2048] (for score streaming).
// MODE 0: A = fp32 x[201][1024]; MODE 1: A = bf16 planes [2][208][1024].
template<int MODE>
__global__ __launch_bounds__(256)
void k_gemm_mfma(const float* __restrict__ Xf, const unsigned short* __restrict__ Apl,
                 const float* __restrict__ Wl, const float* __restrict__ bl,
                 const float* __restrict__ Wr, const float* __restrict__ br,
                 unsigned short* __restrict__ outT, unsigned short* __restrict__ outR) {
    __shared__ short lA[2 * HROWS * 40];
    __shared__ short lB[2 * 16 * 40];

    int tx = threadIdx.x;
    int panel = blockIdx.x >> 1;
    int half  = blockIdx.x & 1;
    int row0  = half * HROWS;
    int ntiles = half ? 6 : 7;
    int wv = tx >> 6, lane = tx & 63;
    int colpan = (panel & 63) * 16;
    const float* Wbase = (panel < 64) ? Wl : Wr;

    int gX[4], lX[4], rowv[4];
    #pragma unroll
    for (int j = 0; j < 4; ++j) {
        int idx = tx + 256 * j;
        if (MODE == 0) {
            int r = idx >> 3, seg = idx & 7;
            rowv[j] = row0 + r;
            gX[j] = (row0 + r) * 1024 + seg * 4;
            lX[j] = r * 40 + seg * 4;
        } else {
            int p = (idx >= 448);
            int rem = idx - p * 448;
            int r = rem >> 2, seg = rem & 3;
            rowv[j] = row0 + r;
            gX[j] = (p * MPAD + row0 + r) * 1024 + seg * 8;
            lX[j] = p * (HROWS * 40) + r * 40 + seg * 8;
        }
    }
    int wcol = tx >> 3, wseg = tx & 7;
    size_t goffW = (size_t)(colpan + wcol) * 1024 + wseg * 4;

    float4  af[4];
    short8v ap[4];
    float4  wreg;

    auto loadChunk = [&](int k0) {
        #pragma unroll
        for (int j = 0; j < 3; ++j) {
            if (MODE == 0) {
                af[j] = (rowv[j] < 201) ? *(const float4*)&Xf[gX[j] + k0]
                                        : make_float4(0.f, 0.f, 0.f, 0.f);
            } else {
                ap[j] = (rowv[j] < 201) ? *(const short8v*)&Apl[gX[j] + k0]
                                        : short8v{0,0,0,0,0,0,0,0};
            }
        }
        if (tx < 128) {
            if (MODE == 0) {
                af[3] = (rowv[3] < 201) ? *(const float4*)&Xf[gX[3] + k0]
                                        : make_float4(0.f, 0.f, 0.f, 0.f);
            } else {
                ap[3] = (rowv[3] < 201) ? *(const short8v*)&Apl[gX[3] + k0]
                                        : short8v{0,0,0,0,0,0,0,0};
            }
            wreg = *(const float4*)&Wbase[goffW + k0];
        }
    };
    auto storeSeg = [&](int j) {
        if (MODE == 0) {
            ushort4 hi, lo;
            hi.x = f2bf(af[j].x); lo.x = f2bf(af[j].x - bf2f(hi.x));
            hi.y = f2bf(af[j].y); lo.y = f2bf(af[j].y - bf2f(hi.y));
            hi.z = f2bf(af[j].z); lo.z = f2bf(af[j].z - bf2f(hi.z));
            hi.w = f2bf(af[j].w); lo.w = f2bf(af[j].w - bf2f(hi.w));
            *(ushort4*)&lA[lX[j]]              = hi;
            *(ushort4*)&lA[HROWS * 40 + lX[j]] = lo;
        } else {
            *(short8v*)&lA[lX[j]] = ap[j];
        }
    };
    auto storeChunk = [&]() {
        #pragma unroll
        for (int j = 0; j < 3; ++j) storeSeg(j);
        if (tx < 128) {
            storeSeg(3);
            ushort4 hi, lo;
            hi.x = f2bf(wreg.x); lo.x = f2bf(wreg.x - bf2f(hi.x));
            hi.y = f2bf(wreg.y); lo.y = f2bf(wreg.y - bf2f(hi.y));
            hi.z = f2bf(wreg.z); lo.z = f2bf(wreg.z - bf2f(hi.z));
            hi.w = f2bf(wreg.w); lo.w = f2bf(wreg.w - bf2f(hi.w));
            *(ushort4*)&lB[wcol * 40 + wseg * 4]        = hi;
            *(ushort4*)&lB[(16 + wcol) * 40 + wseg * 4] = lo;
        }
    };

    float4v acc[2] = {};
    int row16 = lane & 15;
    int k8    = (lane >> 4) * 8;

    loadChunk(0);
    for (int c = 0; c < 32; ++c) {
        __syncthreads();
        storeChunk();
        __syncthreads();
        if (c < 31) loadChunk((c + 1) * 32);
        short8v bh  = *(const short8v*)&lB[row16 * 40 + k8];
        short8v blo = *(const short8v*)&lB[(16 + row16) * 40 + k8];
        #pragma unroll
        for (int i = 0; i < 2; ++i) {
            int t = wv + 4 * i;
            if (t < ntiles) {
                short8v ah = *(const short8v*)&lA[(t * 16 + row16) * 40 + k8];
                short8v al = *(const short8v*)&lA[HROWS * 40 + (t * 16 + row16) * 40 + k8];
                acc[i] = __builtin_amdgcn_mfma_f32_16x16x32_bf16(ah, bh,  acc[i], 0, 0, 0);
                acc[i] = __builtin_amdgcn_mfma_f32_16x16x32_bf16(al, bh,  acc[i], 0, 0, 0);
                acc[i] = __builtin_amdgcn_mfma_f32_16x16x32_bf16(ah, blo, acc[i], 0, 0, 0);
            }
        }
    }

    // epilogue: T-layout (ushort4 per 4 rows) + R-layout (scalar) hi/lo
    int colg = panel * 16 + row16;
    float bias_val = ((panel < 64) ? bl : br)[colpan + row16];
    unsigned short* Th = outT;
    unsigned short* Tl = outT + (size_t)2048 * KPAD;
    unsigned short* Rh = outR;
    unsigned short* Rl = outR + (size_t)KPAD * 2048;
    #pragma unroll
    for (int i = 0; i < 2; ++i) {
        int t = wv + 4 * i;
        if (t < ntiles) {
            int rowb = row0 + t * 16 + (lane >> 4) * 4;
            ushort4 hi, lo;
            float v0 = acc[i][0] + bias_val, v1 = acc[i][1] + bias_val;
            float v2 = acc[i][2] + bias_val, v3 = acc[i][3] + bias_val;
            hi.x = f2bf(v0); lo.x = f2bf(v0 - bf2f(hi.x));
            hi.y = f2bf(v1); lo.y = f2bf(v1 - bf2f(hi.y));
            hi.z = f2bf(v2); lo.z = f2bf(v2 - bf2f(hi.z));
            hi.w = f2bf(v3); lo.w = f2bf(v3 - bf2f(hi.w));
            *(ushort4*)&Th[(size_t)colg * KPAD + rowb] = hi;
            *(ushort4*)&Tl[(size_t)colg * KPAD + rowb] = lo;
            Rh[(size_t)(rowb + 0) * 2048 + colg] = hi.x;
            Rh[(size_t)(rowb + 1) * 2048 + colg] = hi.y;
            Rh[(size_t)(rowb + 2) * 2048 + colg] = hi.z;
            Rh[(size_t)(rowb + 3) * 2048 + colg] = hi.w;
            Rl[(size_t)(rowb + 0) * 2048 + colg] = lo.x;
            Rl[(size_t)(rowb + 1) * 2048 + colg] = lo.y;
            Rl[(size_t)(rowb + 2) * 2048 + colg] = lo.z;
            Rl[(size_t)(rowb + 3) * 2048 + colg] = lo.w;
        }
    }
}

// ---------------- dense GATv2: on-the-fly mask + scores + softmax + MFMA agg ------
// Block = (head h, dtile of 8 dsts). Thread t owns source s=t (t<224).
// LAYER1=1: relu + write hpl planes [2][208][1024]. LAYER1=0: classifier partials.
template<int LAYER1>
__global__ __launch_bounds__(256)
void k_score(const unsigned short* __restrict__ T,   // [2][2048][KPAD]
             const unsigned short* __restrict__ R,   // [2][KPAD][2048]
             const int* __restrict__ eids, int E, int N,
             const float* __restrict__ att, const float* __restrict__ bias,
             unsigned short* __restrict__ hpl,
             const float* __restrict__ clfW, float* __restrict__ part) {
    __shared__ int   cntL[8][224];
    __shared__ float xrt[128][8];
    __shared__ float a2[128][2];           // (a, 0.4a)
    __shared__ float axr_l[8];
    __shared__ float Sm[8][256];
    __shared__ float smax_l[8], inv_l[8];
    __shared__ unsigned short aP[2][16][232];
    __shared__ float ps[4][2];

    int tx = threadIdx.x;
    int bid = blockIdx.x;
    int h = bid & 7, dt = bid >> 3, d0 = dt * 8;
    int w = tx >> 6, lane = tx & 63;
    const unsigned short* Th = T;
    const unsigned short* Tl = T + (size_t)2048 * KPAD;
    const unsigned short* Rh = R;
    const unsigned short* Rl = R + (size_t)KPAD * 2048;
    const int* srcA = eids;
    const int* dstA = eids + E;

    for (int k = tx; k < 8 * 224; k += 256) ((int*)cntL)[k] = 0;
    if (tx < 128) { float a = att[h * 128 + tx]; a2[tx][0] = a; a2[tx][1] = 0.4f * a; }
    for (int k = tx; k < 2 * 8 * 232; k += 256) {   // zero alpha rows 8..15
        int pl = k / (8 * 232), rem = k % (8 * 232);
        aP[pl][8 + rem / 232][rem % 232] = 0;
    }
    #pragma unroll
    for (int k = 0; k < 4; ++k) {                   // stage xr[c][j]
        int idx = tx + 256 * k;                     // 0..1023
        int c = idx >> 3, j = idx & 7;
        size_t o = (size_t)(d0 + j) * 2048 + 1024 + h * 128 + c;
        xrt[c][j] = bf2f(Rh[o]) + bf2f(Rl[o]);
    }
    __syncthreads();

    // on-the-fly multiplicity mask for rows d0..d0+7
    for (int e = tx; e < E + N; e += 256) {
        int d = (e < E) ? dstA[e] : (e - E);
        if ((unsigned)(d - d0) < 8u) {
            int s = (e < E) ? srcA[e] : (e - E);
            atomicAdd(&cntL[d - d0][s], 1);
        }
    }
    if (tx < 64) {                                  // axr[j] = <a, xr[j]>
        int j = tx >> 3, seg = tx & 7;
        float s = 0.f;
        for (int c = seg * 16; c < seg * 16 + 16; ++c) s += a2[c][0] * xrt[c][j];
        s += __shfl_xor(s, 1, 64);
        s += __shfl_xor(s, 2, 64);
        s += __shfl_xor(s, 4, 64);
        if (seg == 0) axr_l[j] = s;
    }
    __syncthreads();

    // scores: S = 0.6*(axl+axr) + sum 0.4*a*|xl+xr|
    float sc[8] = {};
    float axl = 0.f;
    if (tx < KPAD) {
        size_t base = (size_t)tx * 2048 + h * 128;
        #pragma unroll 4
        for (int q = 0; q < 16; ++q) {
            short8v vh = *(const short8v*)&Rh[base + q * 8];
            short8v vl = *(const short8v*)&Rl[base + q * 8];
            #pragma unroll
            for (int u = 0; u < 8; ++u) {
                int c = q * 8 + u;
                float xv = bf2f((unsigned short)vh[u]) + bf2f((unsigned short)vl[u]);
                float2 av = *(const float2*)&a2[c][0];
                axl = fmaf(av.x, xv, axl);
                float4 xa = *(const float4*)&xrt[c][0];
                float4 xb = *(const float4*)&xrt[c][4];
                sc[0] = fmaf(av.y, fabsf(xv + xa.x), sc[0]);
                sc[1] = fmaf(av.y, fabsf(xv + xa.y), sc[1]);
                sc[2] = fmaf(av.y, fabsf(xv + xa.z), sc[2]);
                sc[3] = fmaf(av.y, fabsf(xv + xa.w), sc[3]);
                sc[4] = fmaf(av.y, fabsf(xv + xb.x), sc[4]);
                sc[5] = fmaf(av.y, fabsf(xv + xb.y), sc[5]);
                sc[6] = fmaf(av.y, fabsf(xv + xb.z), sc[6]);
                sc[7] = fmaf(av.y, fabsf(xv + xb.w), sc[7]);
            }
        }
    }
    float cnt[8];
    #pragma unroll
    for (int j = 0; j < 8; ++j) {
        float c_ = (tx < KPAD) ? (float)cntL[j][tx] : 0.f;
        cnt[j] = c_;
        sc[j] = 0.6f * (axl + axr_l[j]) + sc[j];
        Sm[j][tx] = (c_ > 0.f) ? sc[j] : -__builtin_huge_valf();
    }
    __syncthreads();
    #pragma unroll
    for (int rr = 0; rr < 2; ++rr) {            // masked row max
        int j = w * 2 + rr;
        float v = fmaxf(fmaxf(Sm[j][lane], Sm[j][lane + 64]),
                        fmaxf(Sm[j][lane + 128], Sm[j][lane + 192]));
        #pragma unroll
        for (int hop = 1; hop <= 32; hop <<= 1) v = fmaxf(v, __shfl_xor(v, hop, 64));
        if (lane == 0) smax_l[j] = v;
    }
    __syncthreads();
    float pj[8];
    #pragma unroll
    for (int j = 0; j < 8; ++j) {
        float p = (cnt[j] > 0.f) ? cnt[j] * __expf(sc[j] - smax_l[j]) : 0.f;
        pj[j] = p;
        Sm[j][tx] = p;
    }
    __syncthreads();
    #pragma unroll
    for (int rr = 0; rr < 2; ++rr) {            // denominators
        int j = w * 2 + rr;
        float v = Sm[j][lane] + Sm[j][lane + 64] + Sm[j][lane + 128] + Sm[j][lane + 192];
        #pragma unroll
        for (int hop = 1; hop <= 32; hop <<= 1) v += __shfl_xor(v, hop, 64);
        if (lane == 0) inv_l[j] = 1.f / (v + 1e-16f);
    }
    __syncthreads();
    if (tx < KPAD) {                            // alpha hi/lo
        #pragma unroll
        for (int j = 0; j < 8; ++j) {
            float a = pj[j] * inv_l[j];
            unsigned short hi = f2bf(a);
            unsigned short lo = f2bf(a - bf2f(hi));
            aP[0][j][tx] = hi;
            aP[1][j][tx] = lo;
        }
    }
    __syncthreads();

    // MFMA aggregation: C[16 d][32 c per wave] = alpha[16][224] @ xlT
    float4v acc[2] = {};
    int row16 = lane & 15;
    int k8 = (lane >> 4) * 8;
    for (int kc = 0; kc < 7; ++kc) {
        short8v Ah = *(const short8v*)&aP[0][row16][kc * 32 + k8];
        short8v Al = *(const short8v*)&aP[1][row16][kc * 32 + k8];
        #pragma unroll
        for (int cf = 0; cf < 2; ++cf) {
            int c_abs = h * 128 + w * 32 + cf * 16 + row16;
            size_t o = (size_t)c_abs * KPAD + kc * 32 + k8;
            short8v Bh = *(const short8v*)&Th[o];
            short8v Bl = *(const short8v*)&Tl[o];
            acc[cf] = __builtin_amdgcn_mfma_f32_16x16x32_bf16(Ah, Bh, acc[cf], 0, 0, 0);
            acc[cf] = __builtin_amdgcn_mfma_f32_16x16x32_bf16(Al, Bh, acc[cf], 0, 0, 0);
            acc[cf] = __builtin_amdgcn_mfma_f32_16x16x32_bf16(Ah, Bl, acc[cf], 0, 0, 0);
        }
    }

    int r = (lane >> 4) * 4;
    if (LAYER1) {
        if (r < 8) {
            #pragma unroll
            for (int cf = 0; cf < 2; ++cf) {
                int c_abs = h * 128 + w * 32 + cf * 16 + (lane & 15);
                float bv = bias[c_abs];
                #pragma unroll
                for (int j = 0; j < 4; ++j) {
                    int d = d0 + r + j;
                    float val = fmaxf(acc[cf][j] + bv, 0.f);
                    unsigned short hi = f2bf(val);
                    unsigned short lo = f2bf(val - bf2f(hi));
                    hpl[(size_t)d * 1024 + c_abs]          = hi;
                    hpl[(size_t)(MPAD + d) * 1024 + c_abs] = lo;
                }
            }
        }
    } else {
        float p0 = 0.f, p1 = 0.f;
        if (r < 8) {
            #pragma unroll
            for (int cf = 0; cf < 2; ++cf) {
                int c_abs = h * 128 + w * 32 + cf * 16 + (lane & 15);
                float bv = bias[c_abs];
                float c0 = clfW[c_abs], c1 = clfW[1024 + c_abs];
                #pragma unroll
                for (int j = 0; j < 4; ++j) {
                    int d = d0 + r + j;
                    if (d < 201) {
                        float val = acc[cf][j] + bv;
                        float wgt = (d == 200) ? (1.f / 3.f) : (1.f / 300.f);
                        p0 += wgt * val * c0;
                        p1 += wgt * val * c1;
                    }
                }
            }
        }
        #pragma unroll
        for (int hop = 1; hop <= 32; hop <<= 1) {
            p0 += __shfl_xor(p0, hop, 64);
            p1 += __shfl_xor(p1, hop, 64);
        }
        if (lane == 0) { ps[w][0] = p0; ps[w][1] = p1; }
        __syncthreads();
        if (tx == 0) {
            part[bid]      = ps[0][0] + ps[1][0] + ps[2][0] + ps[3][0];
            part[NB + bid] = ps[0][1] + ps[1][1] + ps[2][1] + ps[3][1];
        }
    }
}

// ---------------- finalize ----------------
__global__ __launch_bounds__(256)
void k_fin(const float* __restrict__ part, const float* __restrict__ clfb,
           float* __restrict__ outp) {
    int t = threadIdx.x;
    float s0 = (t < NB) ? part[t] : 0.f;
    float s1 = (t < NB) ? part[NB + t] : 0.f;
    __shared__ float r0[256], r1[256];
    r0[t] = s0; r1[t] = s1;
    __syncthreads();
    for (int off = 128; off > 0; off >>= 1) {
        if (t < off) { r0[t] += r0[t + off]; r1[t] += r1[t + off]; }
        __syncthreads();
    }
    if (t == 0) { outp[0] = r0[0] + clfb[0]; outp[1] = r1[0] + clfb[1]; }
}

extern "C" void kernel_launch(void* const* d_in, const int* in_sizes, int n_in,
                              void* d_out, int out_size, void* d_ws, size_t ws_size,
                              hipStream_t stream) {
    const float* x     = (const float*)d_in[0];
    const int*   eids  = (const int*)d_in[1];
    const float* W1l   = (const float*)d_in[2];
    const float* b1l   = (const float*)d_in[3];
    const float* W1r   = (const float*)d_in[4];
    const float* b1r   = (const float*)d_in[5];
    const float* att1  = (const float*)d_in[6];
    const float* bias1 = (const float*)d_in[7];
    const float* W2l   = (const float*)d_in[8];
    const float* b2l   = (const float*)d_in[9];
    const float* W2r   = (const float*)d_in[10];
    const float* b2r   = (const float*)d_in[11];
    const float* att2  = (const float*)d_in[12];
    const float* bias2 = (const float*)d_in[13];
    const float* clfW  = (const float*)d_in[14];
    const float* clfb  = (const float*)d_in[15];
    float* outp = (float*)d_out;

    int N = in_sizes[0] / 1024;   // 201
    int E = in_sizes[1] / 2;      // 40200

    char* wsp = (char*)d_ws;
    unsigned short* T1  = (unsigned short*)wsp; wsp += (size_t)2 * 2048 * KPAD * 2;
    unsigned short* R1  = (unsigned short*)wsp; wsp += (size_t)2 * KPAD * 2048 * 2;
    unsigned short* hpl = (unsigned short*)wsp; wsp += (size_t)2 * MPAD * 1024 * 2;
    unsigned short* T2  = (unsigned short*)wsp; wsp += (size_t)2 * 2048 * KPAD * 2;
    unsigned short* R2  = (unsigned short*)wsp; wsp += (size_t)2 * KPAD * 2048 * 2;
    float* part = (float*)wsp;                  wsp += (size_t)2 * NB * 4;

    k_gemm_mfma<0><<<256, 256, 0, stream>>>(x, (const unsigned short*)nullptr,
                                            W1l, b1l, W1r, b1r, T1, R1);
    k_score<1><<<NB, 256, 0, stream>>>(T1, R1, eids, E, N, att1, bias1,
                                       hpl, (const float*)nullptr, (float*)nullptr);
    k_gemm_mfma<1><<<256, 256, 0, stream>>>((const float*)nullptr, hpl,
                                            W2l, b2l, W2r, b2r, T2, R2);
    k_score<0><<<NB, 256, 0, stream>>>(T2, R2, eids, E, N, att2, bias2,
                                       (unsigned short*)nullptr, clfW, part);
    k_fin<<<1, 256, 0, stream>>>(part, clfb, outp);
}

// Round 11
// 266.699 us; speedup vs baseline: 1.0905x; 1.0905x over previous
//
#include <hip/hip_runtime.h>
#include <hip/hip_bf16.h>

#define HEADS 8
#define MPAD  208   // padded node count (13*16)
#define KPAD  224   // padded s-dim (7*32)
#define HROWS 112   // rows per M-half in gemm
#define NB    208   // score blocks: 26 dtiles x 8 heads

typedef __attribute__((ext_vector_type(8))) short short8v;
typedef __attribute__((ext_vector_type(4))) float float4v;

static __device__ __forceinline__ unsigned short f2bf(float f) {
    unsigned int u = __float_as_uint(f);
    u += 0x7FFF + ((u >> 16) & 1);          // RNE
    return (unsigned short)(u >> 16);
}
static __device__ __forceinline__ float bf2f(unsigned short h) {
    return __uint_as_float(((unsigned int)h) << 16);
}

// ---------------- multiplicity matrix (one block) + d_out init ----------------
__global__ __launch_bounds__(1024)
void k_mask(const int* __restrict__ eids, int E, int N,
            int* __restrict__ M, const float* __restrict__ clfb,
            float* __restrict__ outp) {
    int t = threadIdx.x;
    for (int i = t; i < MPAD * KPAD; i += 1024) M[i] = 0;
    __syncthreads();
    const int* srcA = eids;
    const int* dstA = eids + E;
    for (int e = t; e < E + N; e += 1024) {
        int d = (e < E) ? dstA[e] : (e - E);   // self-loops appended
        int s = (e < E) ? srcA[e] : (e - E);
        atomicAdd(&M[d * KPAD + s], 1);
    }
    if (t == 0) { outp[0] = clfb[0]; outp[1] = clfb[1]; }
}

// ---------------- MFMA split-bf16 dual GEMM, W-stationary ----------------
// Writes T-layout planes outT[2][2048][KPAD] (for MFMA agg B-frags) AND
// R-layout planes outR[2][KPAD][2048] (for score streaming).
// MODE 0: A = fp32 x[201][1024]; MODE 1: A = bf16 planes [2][208][1024].
template<int MODE>
__global__ __launch_bounds__(256)
void k_gemm_mfma(const float* __restrict__ Xf, const unsigned short* __restrict__ Apl,
                 const float* __restrict__ Wl, const float* __restrict__ bl,
                 const float* __restrict__ Wr, const float* __restrict__ br,
                 unsigned short* __restrict__ outT, unsigned short* __restrict__ outR) {
    __shared__ short lA[2 * HROWS * 40];
    __shared__ short lB[2 * 16 * 40];

    int tx = threadIdx.x;
    int panel = blockIdx.x >> 1;
    int half  = blockIdx.x & 1;
    int row0  = half * HROWS;
    int ntiles = half ? 6 : 7;
    int wv = tx >> 6, lane = tx & 63;
    int colpan = (panel & 63) * 16;
    const float* Wbase = (panel < 64) ? Wl : Wr;

    int gX[4], lX[4], rowv[4];
    #pragma unroll
    for (int j = 0; j < 4; ++j) {
        int idx = tx + 256 * j;
        if (MODE == 0) {
            int r = idx >> 3, seg = idx & 7;
            rowv[j] = row0 + r;
            gX[j] = (row0 + r) * 1024 + seg * 4;
            lX[j] = r * 40 + seg * 4;
        } else {
            int p = (idx >= 448);
            int rem = idx - p * 448;
            int r = rem >> 2, seg = rem & 3;
            rowv[j] = row0 + r;
            gX[j] = (p * MPAD + row0 + r) * 1024 + seg * 8;
            lX[j] = p * (HROWS * 40) + r * 40 + seg * 8;
        }
    }
    int wcol = tx >> 3, wseg = tx & 7;
    size_t goffW = (size_t)(colpan + wcol) * 1024 + wseg * 4;

    float4  af[4];
    short8v ap[4];
    float4  wreg;

    auto loadChunk = [&](int k0) {
        #pragma unroll
        for (int j = 0; j < 3; ++j) {
            if (MODE == 0) {
                af[j] = (rowv[j] < 201) ? *(const float4*)&Xf[gX[j] + k0]
                                        : make_float4(0.f, 0.f, 0.f, 0.f);
            } else {
                ap[j] = (rowv[j] < 201) ? *(const short8v*)&Apl[gX[j] + k0]
                                        : short8v{0,0,0,0,0,0,0,0};
            }
        }
        if (tx < 128) {
            if (MODE == 0) {
                af[3] = (rowv[3] < 201) ? *(const float4*)&Xf[gX[3] + k0]
                                        : make_float4(0.f, 0.f, 0.f, 0.f);
            } else {
                ap[3] = (rowv[3] < 201) ? *(const short8v*)&Apl[gX[3] + k0]
                                        : short8v{0,0,0,0,0,0,0,0};
            }
            wreg = *(const float4*)&Wbase[goffW + k0];
        }
    };
    auto storeSeg = [&](int j) {
        if (MODE == 0) {
            ushort4 hi, lo;
            hi.x = f2bf(af[j].x); lo.x = f2bf(af[j].x - bf2f(hi.x));
            hi.y = f2bf(af[j].y); lo.y = f2bf(af[j].y - bf2f(hi.y));
            hi.z = f2bf(af[j].z); lo.z = f2bf(af[j].z - bf2f(hi.z));
            hi.w = f2bf(af[j].w); lo.w = f2bf(af[j].w - bf2f(hi.w));
            *(ushort4*)&lA[lX[j]]              = hi;
            *(ushort4*)&lA[HROWS * 40 + lX[j]] = lo;
        } else {
            *(short8v*)&lA[lX[j]] = ap[j];
        }
    };
    auto storeChunk = [&]() {
        #pragma unroll
        for (int j = 0; j < 3; ++j) storeSeg(j);
        if (tx < 128) {
            storeSeg(3);
            ushort4 hi, lo;
            hi.x = f2bf(wreg.x); lo.x = f2bf(wreg.x - bf2f(hi.x));
            hi.y = f2bf(wreg.y); lo.y = f2bf(wreg.y - bf2f(hi.y));
            hi.z = f2bf(wreg.z); lo.z = f2bf(wreg.z - bf2f(hi.z));
            hi.w = f2bf(wreg.w); lo.w = f2bf(wreg.w - bf2f(hi.w));
            *(ushort4*)&lB[wcol * 40 + wseg * 4]        = hi;
            *(ushort4*)&lB[(16 + wcol) * 40 + wseg * 4] = lo;
        }
    };

    float4v acc[2] = {};
    int row16 = lane & 15;
    int k8    = (lane >> 4) * 8;

    loadChunk(0);
    for (int c = 0; c < 32; ++c) {
        __syncthreads();
        storeChunk();
        __syncthreads();
        if (c < 31) loadChunk((c + 1) * 32);
        short8v bh  = *(const short8v*)&lB[row16 * 40 + k8];
        short8v blo = *(const short8v*)&lB[(16 + row16) * 40 + k8];
        #pragma unroll
        for (int i = 0; i < 2; ++i) {
            int t = wv + 4 * i;
            if (t < ntiles) {
                short8v ah = *(const short8v*)&lA[(t * 16 + row16) * 40 + k8];
                short8v al = *(const short8v*)&lA[HROWS * 40 + (t * 16 + row16) * 40 + k8];
                acc[i] = __builtin_amdgcn_mfma_f32_16x16x32_bf16(ah, bh,  acc[i], 0, 0, 0);
                acc[i] = __builtin_amdgcn_mfma_f32_16x16x32_bf16(al, bh,  acc[i], 0, 0, 0);
                acc[i] = __builtin_amdgcn_mfma_f32_16x16x32_bf16(ah, blo, acc[i], 0, 0, 0);
            }
        }
    }

    // epilogue: T-layout (ushort4 per 4 rows) + R-layout (scalar) hi/lo
    int colg = panel * 16 + row16;
    float bias_val = ((panel < 64) ? bl : br)[colpan + row16];
    unsigned short* Th = outT;
    unsigned short* Tl = outT + (size_t)2048 * KPAD;
    unsigned short* Rh = outR;
    unsigned short* Rl = outR + (size_t)KPAD * 2048;
    #pragma unroll
    for (int i = 0; i < 2; ++i) {
        int t = wv + 4 * i;
        if (t < ntiles) {
            int rowb = row0 + t * 16 + (lane >> 4) * 4;
            ushort4 hi, lo;
            float v0 = acc[i][0] + bias_val, v1 = acc[i][1] + bias_val;
            float v2 = acc[i][2] + bias_val, v3 = acc[i][3] + bias_val;
            hi.x = f2bf(v0); lo.x = f2bf(v0 - bf2f(hi.x));
            hi.y = f2bf(v1); lo.y = f2bf(v1 - bf2f(hi.y));
            hi.z = f2bf(v2); lo.z = f2bf(v2 - bf2f(hi.z));
            hi.w = f2bf(v3); lo.w = f2bf(v3 - bf2f(hi.w));
            *(ushort4*)&Th[(size_t)colg * KPAD + rowb] = hi;
            *(ushort4*)&Tl[(size_t)colg * KPAD + rowb] = lo;
            Rh[(size_t)(rowb + 0) * 2048 + colg] = hi.x;
            Rh[(size_t)(rowb + 1) * 2048 + colg] = hi.y;
            Rh[(size_t)(rowb + 2) * 2048 + colg] = hi.z;
            Rh[(size_t)(rowb + 3) * 2048 + colg] = hi.w;
            Rl[(size_t)(rowb + 0) * 2048 + colg] = lo.x;
            Rl[(size_t)(rowb + 1) * 2048 + colg] = lo.y;
            Rl[(size_t)(rowb + 2) * 2048 + colg] = lo.z;
            Rl[(size_t)(rowb + 3) * 2048 + colg] = lo.w;
        }
    }
}

// ---------------- dense GATv2: prebuilt mask + scores + softmax + MFMA agg ------
// Block = (head h, dtile of 8 dsts). Thread t owns source s=t (t<224).
// LAYER1=1: relu + write hpl planes [2][208][1024]. LAYER1=0: classifier atomics.
template<int LAYER1>
__global__ __launch_bounds__(256)
void k_score(const unsigned short* __restrict__ T,   // [2][2048][KPAD]
             const unsigned short* __restrict__ R,   // [2][KPAD][2048]
             const int* __restrict__ M,              // [208][224]
             const float* __restrict__ att, const float* __restrict__ bias,
             unsigned short* __restrict__ hpl,
             const float* __restrict__ clfW, float* __restrict__ outp) {
    __shared__ float xrt[128][8];
    __shared__ float a2[128][2];           // (a, 0.4a)
    __shared__ float axr_l[8];
    __shared__ float Sm[8][256];
    __shared__ float smax_l[8], inv_l[8];
    __shared__ unsigned short aP[2][16][232];
    __shared__ float ps[4][2];

    int tx = threadIdx.x;
    int bid = blockIdx.x;
    int h = bid & 7, dt = bid >> 3, d0 = dt * 8;
    int w = tx >> 6, lane = tx & 63;
    const unsigned short* Th = T;
    const unsigned short* Tl = T + (size_t)2048 * KPAD;
    const unsigned short* Rh = R;
    const unsigned short* Rl = R + (size_t)KPAD * 2048;

    if (tx < 128) { float a = att[h * 128 + tx]; a2[tx][0] = a; a2[tx][1] = 0.4f * a; }
    for (int k = tx; k < 2 * 8 * 232; k += 256) {   // zero alpha rows 8..15
        int pl = k / (8 * 232), rem = k % (8 * 232);
        aP[pl][8 + rem / 232][rem % 232] = 0;
    }
    #pragma unroll
    for (int k = 0; k < 4; ++k) {                   // stage xr[c][j]
        int idx = tx + 256 * k;                     // 0..1023
        int c = idx >> 3, j = idx & 7;
        size_t o = (size_t)(d0 + j) * 2048 + 1024 + h * 128 + c;
        xrt[c][j] = bf2f(Rh[o]) + bf2f(Rl[o]);
    }
    __syncthreads();
    if (tx < 64) {                                  // axr[j] = <a, xr[j]>
        int j = tx >> 3, seg = tx & 7;
        float s = 0.f;
        for (int c = seg * 16; c < seg * 16 + 16; ++c) s += a2[c][0] * xrt[c][j];
        s += __shfl_xor(s, 1, 64);
        s += __shfl_xor(s, 2, 64);
        s += __shfl_xor(s, 4, 64);
        if (seg == 0) axr_l[j] = s;
    }
    __syncthreads();

    // scores: S = 0.6*(axl+axr) + sum 0.4*a*|xl+xr|
    float sc[8] = {};
    float axl = 0.f;
    if (tx < KPAD) {
        size_t base = (size_t)tx * 2048 + h * 128;
        #pragma unroll 4
        for (int q = 0; q < 16; ++q) {
            short8v vh = *(const short8v*)&Rh[base + q * 8];
            short8v vl = *(const short8v*)&Rl[base + q * 8];
            #pragma unroll
            for (int u = 0; u < 8; ++u) {
                int c = q * 8 + u;
                float xv = bf2f((unsigned short)vh[u]) + bf2f((unsigned short)vl[u]);
                float2 av = *(const float2*)&a2[c][0];
                axl = fmaf(av.x, xv, axl);
                float4 xa = *(const float4*)&xrt[c][0];
                float4 xb = *(const float4*)&xrt[c][4];
                sc[0] = fmaf(av.y, fabsf(xv + xa.x), sc[0]);
                sc[1] = fmaf(av.y, fabsf(xv + xa.y), sc[1]);
                sc[2] = fmaf(av.y, fabsf(xv + xa.z), sc[2]);
                sc[3] = fmaf(av.y, fabsf(xv + xa.w), sc[3]);
                sc[4] = fmaf(av.y, fabsf(xv + xb.x), sc[4]);
                sc[5] = fmaf(av.y, fabsf(xv + xb.y), sc[5]);
                sc[6] = fmaf(av.y, fabsf(xv + xb.z), sc[6]);
                sc[7] = fmaf(av.y, fabsf(xv + xb.w), sc[7]);
            }
        }
    }
    float cnt[8];
    #pragma unroll
    for (int j = 0; j < 8; ++j) {
        float c_ = (tx < KPAD) ? (float)M[(d0 + j) * KPAD + tx] : 0.f;
        cnt[j] = c_;
        sc[j] = 0.6f * (axl + axr_l[j]) + sc[j];
        Sm[j][tx] = (c_ > 0.f) ? sc[j] : -__builtin_huge_valf();
    }
    __syncthreads();
    #pragma unroll
    for (int rr = 0; rr < 2; ++rr) {            // masked row max
        int j = w * 2 + rr;
        float v = fmaxf(fmaxf(Sm[j][lane], Sm[j][lane + 64]),
                        fmaxf(Sm[j][lane + 128], Sm[j][lane + 192]));
        #pragma unroll
        for (int hop = 1; hop <= 32; hop <<= 1) v = fmaxf(v, __shfl_xor(v, hop, 64));
        if (lane == 0) smax_l[j] = v;
    }
    __syncthreads();
    float pj[8];
    #pragma unroll
    for (int j = 0; j < 8; ++j) {
        float p = (cnt[j] > 0.f) ? cnt[j] * __expf(sc[j] - smax_l[j]) : 0.f;
        pj[j] = p;
        Sm[j][tx] = p;
    }
    __syncthreads();
    #pragma unroll
    for (int rr = 0; rr < 2; ++rr) {            // denominators
        int j = w * 2 + rr;
        float v = Sm[j][lane] + Sm[j][lane + 64] + Sm[j][lane + 128] + Sm[j][lane + 192];
        #pragma unroll
        for (int hop = 1; hop <= 32; hop <<= 1) v += __shfl_xor(v, hop, 64);
        if (lane == 0) inv_l[j] = 1.f / (v + 1e-16f);
    }
    __syncthreads();
    if (tx < KPAD) {                            // alpha hi/lo
        #pragma unroll
        for (int j = 0; j < 8; ++j) {
            float a = pj[j] * inv_l[j];
            unsigned short hi = f2bf(a);
            unsigned short lo = f2bf(a - bf2f(hi));
            aP[0][j][tx] = hi;
            aP[1][j][tx] = lo;
        }
    }
    __syncthreads();

    // MFMA aggregation: C[16 d][32 c per wave] = alpha[16][224] @ xlT
    float4v acc[2] = {};
    int row16 = lane & 15;
    int k8 = (lane >> 4) * 8;
    for (int kc = 0; kc < 7; ++kc) {
        short8v Ah = *(const short8v*)&aP[0][row16][kc * 32 + k8];
        short8v Al = *(const short8v*)&aP[1][row16][kc * 32 + k8];
        #pragma unroll
        for (int cf = 0; cf < 2; ++cf) {
            int c_abs = h * 128 + w * 32 + cf * 16 + row16;
            size_t o = (size_t)c_abs * KPAD + kc * 32 + k8;
            short8v Bh = *(const short8v*)&Th[o];
            short8v Bl = *(const short8v*)&Tl[o];
            acc[cf] = __builtin_amdgcn_mfma_f32_16x16x32_bf16(Ah, Bh, acc[cf], 0, 0, 0);
            acc[cf] = __builtin_amdgcn_mfma_f32_16x16x32_bf16(Al, Bh, acc[cf], 0, 0, 0);
            acc[cf] = __builtin_amdgcn_mfma_f32_16x16x32_bf16(Ah, Bl, acc[cf], 0, 0, 0);
        }
    }

    int r = (lane >> 4) * 4;
    if (LAYER1) {
        if (r < 8) {
            #pragma unroll
            for (int cf = 0; cf < 2; ++cf) {
                int c_abs = h * 128 + w * 32 + cf * 16 + (lane & 15);
                float bv = bias[c_abs];
                #pragma unroll
                for (int j = 0; j < 4; ++j) {
                    int d = d0 + r + j;
                    float val = fmaxf(acc[cf][j] + bv, 0.f);
                    unsigned short hi = f2bf(val);
                    unsigned short lo = f2bf(val - bf2f(hi));
                    hpl[(size_t)d * 1024 + c_abs]          = hi;
                    hpl[(size_t)(MPAD + d) * 1024 + c_abs] = lo;
                }
            }
        }
    } else {
        float p0 = 0.f, p1 = 0.f;
        if (r < 8) {
            #pragma unroll
            for (int cf = 0; cf < 2; ++cf) {
                int c_abs = h * 128 + w * 32 + cf * 16 + (lane & 15);
                float bv = bias[c_abs];
                float c0 = clfW[c_abs], c1 = clfW[1024 + c_abs];
                #pragma unroll
                for (int j = 0; j < 4; ++j) {
                    int d = d0 + r + j;
                    if (d < 201) {
                        float val = acc[cf][j] + bv;
                        float wgt = (d == 200) ? (1.f / 3.f) : (1.f / 300.f);
                        p0 += wgt * val * c0;
                        p1 += wgt * val * c1;
                    }
                }
            }
        }
        #pragma unroll
        for (int hop = 1; hop <= 32; hop <<= 1) {
            p0 += __shfl_xor(p0, hop, 64);
            p1 += __shfl_xor(p1, hop, 64);
        }
        if (lane == 0) { ps[w][0] = p0; ps[w][1] = p1; }
        __syncthreads();
        if (tx == 0) {
            atomicAdd(&outp[0], ps[0][0] + ps[1][0] + ps[2][0] + ps[3][0]);
            atomicAdd(&outp[1], ps[0][1] + ps[1][1] + ps[2][1] + ps[3][1]);
        }
    }
}

extern "C" void kernel_launch(void* const* d_in, const int* in_sizes, int n_in,
                              void* d_out, int out_size, void* d_ws, size_t ws_size,
                              hipStream_t stream) {
    const float* x     = (const float*)d_in[0];
    const int*   eids  = (const int*)d_in[1];
    const float* W1l   = (const float*)d_in[2];
    const float* b1l   = (const float*)d_in[3];
    const float* W1r   = (const float*)d_in[4];
    const float* b1r   = (const float*)d_in[5];
    const float* att1  = (const float*)d_in[6];
    const float* bias1 = (const float*)d_in[7];
    const float* W2l   = (const float*)d_in[8];
    const float* b2l   = (const float*)d_in[9];
    const float* W2r   = (const float*)d_in[10];
    const float* b2r   = (const float*)d_in[11];
    const float* att2  = (const float*)d_in[12];
    const float* bias2 = (const float*)d_in[13];
    const float* clfW  = (const float*)d_in[14];
    const float* clfb  = (const float*)d_in[15];
    float* outp = (float*)d_out;

    int N = in_sizes[0] / 1024;   // 201
    int E = in_sizes[1] / 2;      // 40200

    char* wsp = (char*)d_ws;
    int* M = (int*)wsp;                         wsp += (size_t)MPAD * KPAD * 4;
    unsigned short* T1  = (unsigned short*)wsp; wsp += (size_t)2 * 2048 * KPAD * 2;
    unsigned short* R1  = (unsigned short*)wsp; wsp += (size_t)2 * KPAD * 2048 * 2;
    unsigned short* hpl = (unsigned short*)wsp; wsp += (size_t)2 * MPAD * 1024 * 2;
    unsigned short* T2  = (unsigned short*)wsp; wsp += (size_t)2 * 2048 * KPAD * 2;
    unsigned short* R2  = (unsigned short*)wsp; wsp += (size_t)2 * KPAD * 2048 * 2;

    k_mask<<<1, 1024, 0, stream>>>(eids, E, N, M, clfb, outp);
    k_gemm_mfma<0><<<256, 256, 0, stream>>>(x, (const unsigned short*)nullptr,
                                            W1l, b1l, W1r, b1r, T1, R1);
    k_score<1><<<NB, 256, 0, stream>>>(T1, R1, M, att1, bias1,
                                       hpl, (const float*)nullptr, (float*)nullptr);
    k_gemm_mfma<1><<<256, 256, 0, stream>>>((const float*)nullptr, hpl,
                                            W2l, b2l, W2r, b2r, T2, R2);
    k_score<0><<<NB, 256, 0, stream>>>(T2, R2, M, att2, bias2,
                                       (unsigned short*)nullptr, clfW, outp);
}

// Round 12
// 195.555 us; speedup vs baseline: 1.4872x; 1.3638x over previous
//
#include <hip/hip_runtime.h>
#include <hip/hip_bf16.h>

#define HEADS 8
#define MPAD  208   // padded node count (13*16)
#define KPAD  224   // padded s-dim (7*32)
#define HROWS 112   // rows per M-half in gemm
#define NB    208   // score blocks: 26 dtiles x 8 heads

typedef __attribute__((ext_vector_type(8))) short short8v;
typedef __attribute__((ext_vector_type(4))) float float4v;

static __device__ __forceinline__ unsigned short f2bf(float f) {
    unsigned int u = __float_as_uint(f);
    u += 0x7FFF + ((u >> 16) & 1);          // RNE
    return (unsigned short)(u >> 16);
}
static __device__ __forceinline__ float bf2f(unsigned short h) {
    return __uint_as_float(((unsigned int)h) << 16);
}

// ---------------- multiplicity matrix: parallel zero + count ----------------
__global__ void k_mzero(int* __restrict__ M, const float* __restrict__ clfb,
                        float* __restrict__ outp) {
    int i = blockIdx.x * 1024 + threadIdx.x;
    if (i < MPAD * KPAD) M[i] = 0;
    if (i == 0) { outp[0] = clfb[0]; outp[1] = clfb[1]; }
}

__global__ void k_mcount(const int* __restrict__ eids, int E, int N,
                         int* __restrict__ M) {
    int e = blockIdx.x * 256 + threadIdx.x;
    if (e < E + N) {
        const int* srcA = eids;
        const int* dstA = eids + E;
        int d = (e < E) ? dstA[e] : (e - E);   // self-loops appended
        int s = (e < E) ? srcA[e] : (e - E);
        atomicAdd(&M[d * KPAD + s], 1);
    }
}

// ---------------- MFMA split-bf16 dual GEMM, W-stationary ----------------
// Writes T-layout planes outT[2][2048][KPAD] (for MFMA agg B-frags) AND
// R-layout planes outR[2][KPAD][2048] (for score streaming).
// MODE 0: A = fp32 x[201][1024]; MODE 1: A = bf16 planes [2][208][1024].
template<int MODE>
__global__ __launch_bounds__(256)
void k_gemm_mfma(const float* __restrict__ Xf, const unsigned short* __restrict__ Apl,
                 const float* __restrict__ Wl, const float* __restrict__ bl,
                 const float* __restrict__ Wr, const float* __restrict__ br,
                 unsigned short* __restrict__ outT, unsigned short* __restrict__ outR) {
    __shared__ short lA[2 * HROWS * 40];
    __shared__ short lB[2 * 16 * 40];

    int tx = threadIdx.x;
    int panel = blockIdx.x >> 1;
    int half  = blockIdx.x & 1;
    int row0  = half * HROWS;
    int ntiles = half ? 6 : 7;
    int wv = tx >> 6, lane = tx & 63;
    int colpan = (panel & 63) * 16;
    const float* Wbase = (panel < 64) ? Wl : Wr;

    int gX[4], lX[4], rowv[4];
    #pragma unroll
    for (int j = 0; j < 4; ++j) {
        int idx = tx + 256 * j;
        if (MODE == 0) {
            int r = idx >> 3, seg = idx & 7;
            rowv[j] = row0 + r;
            gX[j] = (row0 + r) * 1024 + seg * 4;
            lX[j] = r * 40 + seg * 4;
        } else {
            int p = (idx >= 448);
            int rem = idx - p * 448;
            int r = rem >> 2, seg = rem & 3;
            rowv[j] = row0 + r;
            gX[j] = (p * MPAD + row0 + r) * 1024 + seg * 8;
            lX[j] = p * (HROWS * 40) + r * 40 + seg * 8;
        }
    }
    int wcol = tx >> 3, wseg = tx & 7;
    size_t goffW = (size_t)(colpan + wcol) * 1024 + wseg * 4;

    float4  af[4];
    short8v ap[4];
    float4  wreg;

    auto loadChunk = [&](int k0) {
        #pragma unroll
        for (int j = 0; j < 3; ++j) {
            if (MODE == 0) {
                af[j] = (rowv[j] < 201) ? *(const float4*)&Xf[gX[j] + k0]
                                        : make_float4(0.f, 0.f, 0.f, 0.f);
            } else {
                ap[j] = (rowv[j] < 201) ? *(const short8v*)&Apl[gX[j] + k0]
                                        : short8v{0,0,0,0,0,0,0,0};
            }
        }
        if (tx < 128) {
            if (MODE == 0) {
                af[3] = (rowv[3] < 201) ? *(const float4*)&Xf[gX[3] + k0]
                                        : make_float4(0.f, 0.f, 0.f, 0.f);
            } else {
                ap[3] = (rowv[3] < 201) ? *(const short8v*)&Apl[gX[3] + k0]
                                        : short8v{0,0,0,0,0,0,0,0};
            }
            wreg = *(const float4*)&Wbase[goffW + k0];
        }
    };
    auto storeSeg = [&](int j) {
        if (MODE == 0) {
            ushort4 hi, lo;
            hi.x = f2bf(af[j].x); lo.x = f2bf(af[j].x - bf2f(hi.x));
            hi.y = f2bf(af[j].y); lo.y = f2bf(af[j].y - bf2f(hi.y));
            hi.z = f2bf(af[j].z); lo.z = f2bf(af[j].z - bf2f(hi.z));
            hi.w = f2bf(af[j].w); lo.w = f2bf(af[j].w - bf2f(hi.w));
            *(ushort4*)&lA[lX[j]]              = hi;
            *(ushort4*)&lA[HROWS * 40 + lX[j]] = lo;
        } else {
            *(short8v*)&lA[lX[j]] = ap[j];
        }
    };
    auto storeChunk = [&]() {
        #pragma unroll
        for (int j = 0; j < 3; ++j) storeSeg(j);
        if (tx < 128) {
            storeSeg(3);
            ushort4 hi, lo;
            hi.x = f2bf(wreg.x); lo.x = f2bf(wreg.x - bf2f(hi.x));
            hi.y = f2bf(wreg.y); lo.y = f2bf(wreg.y - bf2f(hi.y));
            hi.z = f2bf(wreg.z); lo.z = f2bf(wreg.z - bf2f(hi.z));
            hi.w = f2bf(wreg.w); lo.w = f2bf(wreg.w - bf2f(hi.w));
            *(ushort4*)&lB[wcol * 40 + wseg * 4]        = hi;
            *(ushort4*)&lB[(16 + wcol) * 40 + wseg * 4] = lo;
        }
    };

    float4v acc[2] = {};
    int row16 = lane & 15;
    int k8    = (lane >> 4) * 8;

    loadChunk(0);
    for (int c = 0; c < 32; ++c) {
        __syncthreads();
        storeChunk();
        __syncthreads();
        if (c < 31) loadChunk((c + 1) * 32);
        short8v bh  = *(const short8v*)&lB[row16 * 40 + k8];
        short8v blo = *(const short8v*)&lB[(16 + row16) * 40 + k8];
        #pragma unroll
        for (int i = 0; i < 2; ++i) {
            int t = wv + 4 * i;
            if (t < ntiles) {
                short8v ah = *(const short8v*)&lA[(t * 16 + row16) * 40 + k8];
                short8v al = *(const short8v*)&lA[HROWS * 40 + (t * 16 + row16) * 40 + k8];
                acc[i] = __builtin_amdgcn_mfma_f32_16x16x32_bf16(ah, bh,  acc[i], 0, 0, 0);
                acc[i] = __builtin_amdgcn_mfma_f32_16x16x32_bf16(al, bh,  acc[i], 0, 0, 0);
                acc[i] = __builtin_amdgcn_mfma_f32_16x16x32_bf16(ah, blo, acc[i], 0, 0, 0);
            }
        }
    }

    // epilogue: T-layout (ushort4 per 4 rows) + R-layout (scalar) hi/lo
    int colg = panel * 16 + row16;
    float bias_val = ((panel < 64) ? bl : br)[colpan + row16];
    unsigned short* Th = outT;
    unsigned short* Tl = outT + (size_t)2048 * KPAD;
    unsigned short* Rh = outR;
    unsigned short* Rl = outR + (size_t)KPAD * 2048;
    #pragma unroll
    for (int i = 0; i < 2; ++i) {
        int t = wv + 4 * i;
        if (t < ntiles) {
            int rowb = row0 + t * 16 + (lane >> 4) * 4;
            ushort4 hi, lo;
            float v0 = acc[i][0] + bias_val, v1 = acc[i][1] + bias_val;
            float v2 = acc[i][2] + bias_val, v3 = acc[i][3] + bias_val;
            hi.x = f2bf(v0); lo.x = f2bf(v0 - bf2f(hi.x));
            hi.y = f2bf(v1); lo.y = f2bf(v1 - bf2f(hi.y));
            hi.z = f2bf(v2); lo.z = f2bf(v2 - bf2f(hi.z));
            hi.w = f2bf(v3); lo.w = f2bf(v3 - bf2f(hi.w));
            *(ushort4*)&Th[(size_t)colg * KPAD + rowb] = hi;
            *(ushort4*)&Tl[(size_t)colg * KPAD + rowb] = lo;
            Rh[(size_t)(rowb + 0) * 2048 + colg] = hi.x;
            Rh[(size_t)(rowb + 1) * 2048 + colg] = hi.y;
            Rh[(size_t)(rowb + 2) * 2048 + colg] = hi.z;
            Rh[(size_t)(rowb + 3) * 2048 + colg] = hi.w;
            Rl[(size_t)(rowb + 0) * 2048 + colg] = lo.x;
            Rl[(size_t)(rowb + 1) * 2048 + colg] = lo.y;
            Rl[(size_t)(rowb + 2) * 2048 + colg] = lo.z;
            Rl[(size_t)(rowb + 3) * 2048 + colg] = lo.w;
        }
    }
}

// ---------------- dense GATv2: prebuilt mask + scores + softmax + MFMA agg ------
// Block = (head h, dtile of 8 dsts). Thread t owns source s=t (t<224).
// LAYER1=1: relu + write hpl planes [2][208][1024]. LAYER1=0: classifier atomics.
template<int LAYER1>
__global__ __launch_bounds__(256)
void k_score(const unsigned short* __restrict__ T,   // [2][2048][KPAD]
             const unsigned short* __restrict__ R,   // [2][KPAD][2048]
             const int* __restrict__ M,              // [208][224]
             const float* __restrict__ att, const float* __restrict__ bias,
             unsigned short* __restrict__ hpl,
             const float* __restrict__ clfW, float* __restrict__ outp) {
    __shared__ float xrt[128][8];
    __shared__ float a2[128][2];           // (a, 0.4a)
    __shared__ float axr_l[8];
    __shared__ float Sm[8][256];
    __shared__ float smax_l[8], inv_l[8];
    __shared__ unsigned short aP[2][16][232];
    __shared__ float ps[4][2];

    int tx = threadIdx.x;
    int bid = blockIdx.x;
    int h = bid & 7, dt = bid >> 3, d0 = dt * 8;
    int w = tx >> 6, lane = tx & 63;
    const unsigned short* Th = T;
    const unsigned short* Tl = T + (size_t)2048 * KPAD;
    const unsigned short* Rh = R;
    const unsigned short* Rl = R + (size_t)KPAD * 2048;

    if (tx < 128) { float a = att[h * 128 + tx]; a2[tx][0] = a; a2[tx][1] = 0.4f * a; }
    for (int k = tx; k < 2 * 8 * 232; k += 256) {   // zero alpha rows 8..15
        int pl = k / (8 * 232), rem = k % (8 * 232);
        aP[pl][8 + rem / 232][rem % 232] = 0;
    }
    #pragma unroll
    for (int k = 0; k < 4; ++k) {                   // stage xr[c][j]
        int idx = tx + 256 * k;                     // 0..1023
        int c = idx >> 3, j = idx & 7;
        size_t o = (size_t)(d0 + j) * 2048 + 1024 + h * 128 + c;
        xrt[c][j] = bf2f(Rh[o]) + bf2f(Rl[o]);
    }
    __syncthreads();
    if (tx < 64) {                                  // axr[j] = <a, xr[j]>
        int j = tx >> 3, seg = tx & 7;
        float s = 0.f;
        for (int c = seg * 16; c < seg * 16 + 16; ++c) s += a2[c][0] * xrt[c][j];
        s += __shfl_xor(s, 1, 64);
        s += __shfl_xor(s, 2, 64);
        s += __shfl_xor(s, 4, 64);
        if (seg == 0) axr_l[j] = s;
    }
    __syncthreads();

    // scores: S = 0.6*(axl+axr) + sum 0.4*a*|xl+xr|
    float sc[8] = {};
    float axl = 0.f;
    if (tx < KPAD) {
        size_t base = (size_t)tx * 2048 + h * 128;
        #pragma unroll 4
        for (int q = 0; q < 16; ++q) {
            short8v vh = *(const short8v*)&Rh[base + q * 8];
            short8v vl = *(const short8v*)&Rl[base + q * 8];
            #pragma unroll
            for (int u = 0; u < 8; ++u) {
                int c = q * 8 + u;
                float xv = bf2f((unsigned short)vh[u]) + bf2f((unsigned short)vl[u]);
                float2 av = *(const float2*)&a2[c][0];
                axl = fmaf(av.x, xv, axl);
                float4 xa = *(const float4*)&xrt[c][0];
                float4 xb = *(const float4*)&xrt[c][4];
                sc[0] = fmaf(av.y, fabsf(xv + xa.x), sc[0]);
                sc[1] = fmaf(av.y, fabsf(xv + xa.y), sc[1]);
                sc[2] = fmaf(av.y, fabsf(xv + xa.z), sc[2]);
                sc[3] = fmaf(av.y, fabsf(xv + xa.w), sc[3]);
                sc[4] = fmaf(av.y, fabsf(xv + xb.x), sc[4]);
                sc[5] = fmaf(av.y, fabsf(xv + xb.y), sc[5]);
                sc[6] = fmaf(av.y, fabsf(xv + xb.z), sc[6]);
                sc[7] = fmaf(av.y, fabsf(xv + xb.w), sc[7]);
            }
        }
    }
    float cnt[8];
    #pragma unroll
    for (int j = 0; j < 8; ++j) {
        float c_ = (tx < KPAD) ? (float)M[(d0 + j) * KPAD + tx] : 0.f;
        cnt[j] = c_;
        sc[j] = 0.6f * (axl + axr_l[j]) + sc[j];
        Sm[j][tx] = (c_ > 0.f) ? sc[j] : -__builtin_huge_valf();
    }
    __syncthreads();
    #pragma unroll
    for (int rr = 0; rr < 2; ++rr) {            // masked row max
        int j = w * 2 + rr;
        float v = fmaxf(fmaxf(Sm[j][lane], Sm[j][lane + 64]),
                        fmaxf(Sm[j][lane + 128], Sm[j][lane + 192]));
        #pragma unroll
        for (int hop = 1; hop <= 32; hop <<= 1) v = fmaxf(v, __shfl_xor(v, hop, 64));
        if (lane == 0) smax_l[j] = v;
    }
    __syncthreads();
    float pj[8];
    #pragma unroll
    for (int j = 0; j < 8; ++j) {
        float p = (cnt[j] > 0.f) ? cnt[j] * __expf(sc[j] - smax_l[j]) : 0.f;
        pj[j] = p;
        Sm[j][tx] = p;
    }
    __syncthreads();
    #pragma unroll
    for (int rr = 0; rr < 2; ++rr) {            // denominators
        int j = w * 2 + rr;
        float v = Sm[j][lane] + Sm[j][lane + 64] + Sm[j][lane + 128] + Sm[j][lane + 192];
        #pragma unroll
        for (int hop = 1; hop <= 32; hop <<= 1) v += __shfl_xor(v, hop, 64);
        if (lane == 0) inv_l[j] = 1.f / (v + 1e-16f);
    }
    __syncthreads();
    if (tx < KPAD) {                            // alpha hi/lo
        #pragma unroll
        for (int j = 0; j < 8; ++j) {
            float a = pj[j] * inv_l[j];
            unsigned short hi = f2bf(a);
            unsigned short lo = f2bf(a - bf2f(hi));
            aP[0][j][tx] = hi;
            aP[1][j][tx] = lo;
        }
    }
    __syncthreads();

    // MFMA aggregation: C[16 d][32 c per wave] = alpha[16][224] @ xlT
    float4v acc[2] = {};
    int row16 = lane & 15;
    int k8 = (lane >> 4) * 8;
    for (int kc = 0; kc < 7; ++kc) {
        short8v Ah = *(const short8v*)&aP[0][row16][kc * 32 + k8];
        short8v Al = *(const short8v*)&aP[1][row16][kc * 32 + k8];
        #pragma unroll
        for (int cf = 0; cf < 2; ++cf) {
            int c_abs = h * 128 + w * 32 + cf * 16 + row16;
            size_t o = (size_t)c_abs * KPAD + kc * 32 + k8;
            short8v Bh = *(const short8v*)&Th[o];
            short8v Bl = *(const short8v*)&Tl[o];
            acc[cf] = __builtin_amdgcn_mfma_f32_16x16x32_bf16(Ah, Bh, acc[cf], 0, 0, 0);
            acc[cf] = __builtin_amdgcn_mfma_f32_16x16x32_bf16(Al, Bh, acc[cf], 0, 0, 0);
            acc[cf] = __builtin_amdgcn_mfma_f32_16x16x32_bf16(Ah, Bl, acc[cf], 0, 0, 0);
        }
    }

    int r = (lane >> 4) * 4;
    if (LAYER1) {
        if (r < 8) {
            #pragma unroll
            for (int cf = 0; cf < 2; ++cf) {
                int c_abs = h * 128 + w * 32 + cf * 16 + (lane & 15);
                float bv = bias[c_abs];
                #pragma unroll
                for (int j = 0; j < 4; ++j) {
                    int d = d0 + r + j;
                    float val = fmaxf(acc[cf][j] + bv, 0.f);
                    unsigned short hi = f2bf(val);
                    unsigned short lo = f2bf(val - bf2f(hi));
                    hpl[(size_t)d * 1024 + c_abs]          = hi;
                    hpl[(size_t)(MPAD + d) * 1024 + c_abs] = lo;
                }
            }
        }
    } else {
        float p0 = 0.f, p1 = 0.f;
        if (r < 8) {
            #pragma unroll
            for (int cf = 0; cf < 2; ++cf) {
                int c_abs = h * 128 + w * 32 + cf * 16 + (lane & 15);
                float bv = bias[c_abs];
                float c0 = clfW[c_abs], c1 = clfW[1024 + c_abs];
                #pragma unroll
                for (int j = 0; j < 4; ++j) {
                    int d = d0 + r + j;
                    if (d < 201) {
                        float val = acc[cf][j] + bv;
                        float wgt = (d == 200) ? (1.f / 3.f) : (1.f / 300.f);
                        p0 += wgt * val * c0;
                        p1 += wgt * val * c1;
                    }
                }
            }
        }
        #pragma unroll
        for (int hop = 1; hop <= 32; hop <<= 1) {
            p0 += __shfl_xor(p0, hop, 64);
            p1 += __shfl_xor(p1, hop, 64);
        }
        if (lane == 0) { ps[w][0] = p0; ps[w][1] = p1; }
        __syncthreads();
        if (tx == 0) {
            atomicAdd(&outp[0], ps[0][0] + ps[1][0] + ps[2][0] + ps[3][0]);
            atomicAdd(&outp[1], ps[0][1] + ps[1][1] + ps[2][1] + ps[3][1]);
        }
    }
}

extern "C" void kernel_launch(void* const* d_in, const int* in_sizes, int n_in,
                              void* d_out, int out_size, void* d_ws, size_t ws_size,
                              hipStream_t stream) {
    const float* x     = (const float*)d_in[0];
    const int*   eids  = (const int*)d_in[1];
    const float* W1l   = (const float*)d_in[2];
    const float* b1l   = (const float*)d_in[3];
    const float* W1r   = (const float*)d_in[4];
    const float* b1r   = (const float*)d_in[5];
    const float* att1  = (const float*)d_in[6];
    const float* bias1 = (const float*)d_in[7];
    const float* W2l   = (const float*)d_in[8];
    const float* b2l   = (const float*)d_in[9];
    const float* W2r   = (const float*)d_in[10];
    const float* b2r   = (const float*)d_in[11];
    const float* att2  = (const float*)d_in[12];
    const float* bias2 = (const float*)d_in[13];
    const float* clfW  = (const float*)d_in[14];
    const float* clfb  = (const float*)d_in[15];
    float* outp = (float*)d_out;

    int N = in_sizes[0] / 1024;   // 201
    int E = in_sizes[1] / 2;      // 40200
    int tot = E + N;

    char* wsp = (char*)d_ws;
    int* M = (int*)wsp;                         wsp += (size_t)MPAD * KPAD * 4;
    unsigned short* T1  = (unsigned short*)wsp; wsp += (size_t)2 * 2048 * KPAD * 2;
    unsigned short* R1  = (unsigned short*)wsp; wsp += (size_t)2 * KPAD * 2048 * 2;
    unsigned short* hpl = (unsigned short*)wsp; wsp += (size_t)2 * MPAD * 1024 * 2;
    unsigned short* T2  = (unsigned short*)wsp; wsp += (size_t)2 * 2048 * KPAD * 2;
    unsigned short* R2  = (unsigned short*)wsp; wsp += (size_t)2 * KPAD * 2048 * 2;

    k_mzero <<<(MPAD * KPAD + 1023) / 1024, 1024, 0, stream>>>(M, clfb, outp);
    k_mcount<<<(tot + 255) / 256, 256, 0, stream>>>(eids, E, N, M);
    k_gemm_mfma<0><<<256, 256, 0, stream>>>(x, (const unsigned short*)nullptr,
                                            W1l, b1l, W1r, b1r, T1, R1);
    k_score<1><<<NB, 256, 0, stream>>>(T1, R1, M, att1, bias1,
                                       hpl, (const float*)nullptr, (float*)nullptr);
    k_gemm_mfma<1><<<256, 256, 0, stream>>>((const float*)nullptr, hpl,
                                            W2l, b2l, W2r, b2r, T2, R2);
    k_score<0><<<NB, 256, 0, stream>>>(T2, R2, M, att2, bias2,
                                       (unsigned short*)nullptr, clfW, outp);
}